// Round 12
// baseline (139.296 us; speedup 1.0000x reference)
//
#include <hip/hip_runtime.h>
#include <hip/hip_fp16.h>

// ---------------------------------------------------------------------------
// ClassificationKNNLoss on MI355X — fused, distance matrix never materialized.
//   k_prep : norms + bf16 convert with granule-XOR swizzle (+ zeroes d_out)
//   k_main : full GEMM; branch-free epilogue (d, exp(-d)->denom, per-thread
//            sorted top-2 keys). R12: 32-col tiles DOUBLE-BUFFERED with raw
//            s_barrier + counted vmcnt(4) (stage latency no longer exposed
//            per tile — untested at 4 blocks/CU; R5's dbuf-null was 2/CU).
//            Stagger bounded to 4-phase window (R11 lesson: unbounded phase
//            decorrelation blows the per-XCD L2: FETCH 32->129MB).
//   k_fin  : per-row top-16 of 512 candidates, label match, loss reduction.
// ---------------------------------------------------------------------------

typedef __attribute__((ext_vector_type(8))) short s8v;       // 8 x bf16 (4 VGPR)
typedef __attribute__((ext_vector_type(4))) float f32x4;     // MFMA acc
typedef __attribute__((ext_vector_type(2))) unsigned u32x2;  // nt store
typedef __attribute__((ext_vector_type(4))) unsigned u32x4;  // nt load

#define NROW 8192
#define NK   256

template <bool B> struct BoolC { static constexpr bool value = B; };

// ws byte offsets
#define OFF_DNP  0                          // f32[8192*8] denom partials (256KB)
#define OFF_NRM  262144                     // f32[8192]
#define OFF_XB   294912                     // u16[8192*256] swizzled bf16 (4.19MB)
#define OFF_CAND (294912 + 4194304)         // u32[8192*512] candidates (16.8MB)

__device__ __forceinline__ unsigned short f2bf(float f) {
  unsigned u = __float_as_uint(f);
  return (unsigned short)((u + 0x7FFFu + ((u >> 16) & 1u)) >> 16);  // RNE
}

__device__ __forceinline__ void gld16(const void* g, void* l) {
  __builtin_amdgcn_global_load_lds(
      (const __attribute__((address_space(1))) unsigned int*)g,
      (__attribute__((address_space(3))) unsigned int*)l, 16, 0, 0);
}

__device__ __forceinline__ unsigned umin32(unsigned a, unsigned b) { return a < b ? a : b; }
__device__ __forceinline__ unsigned umax32(unsigned a, unsigned b) { return a > b ? a : b; }

// ---------------------------------------------------------------- k_prep ----
// xb[(r,k)] stored at u16 index r*256 + ((k>>3) ^ (r&7))*8 + (k&7)
__global__ __launch_bounds__(256) void k_prep(const float* __restrict__ x,
                                              unsigned short* __restrict__ xb,
                                              float* __restrict__ nrm,
                                              float* __restrict__ out) {
  if (blockIdx.x == 0 && threadIdx.x == 0) out[0] = 0.0f;  // replaces memset node
  const int w = threadIdx.x >> 6, l = threadIdx.x & 63;
  const int r = blockIdx.x * 4 + w;
  const float4 xv = *reinterpret_cast<const float4*>(x + r * NK + l * 4);
  float ns = xv.x * xv.x + xv.y * xv.y + xv.z * xv.z + xv.w * xv.w;
  ns += __shfl_xor(ns, 1);  ns += __shfl_xor(ns, 2);  ns += __shfl_xor(ns, 4);
  ns += __shfl_xor(ns, 8);  ns += __shfl_xor(ns, 16); ns += __shfl_xor(ns, 32);
  if (l == 0) nrm[r] = ns;
  ushort4 bv;
  bv.x = f2bf(xv.x); bv.y = f2bf(xv.y); bv.z = f2bf(xv.z); bv.w = f2bf(xv.w);
  const int gs = (l >> 1) ^ (r & 7);
  *reinterpret_cast<ushort4*>(xb + r * NK + gs * 8 + (l & 1) * 4) = bv;
}

// ---------------------------------------------------------------- k_main ----
// 1024 blocks = 128 rb x 8 cs; 256 thr (4 waves); 64 rows/block; 32-col tiles
// double-buffered (16KB each); counted vmcnt keeps prefetch in flight.
__global__ __launch_bounds__(256, 4) void k_main(const unsigned short* __restrict__ xb,
                                                 const float* __restrict__ nrm,
                                                 float* __restrict__ dnp,
                                                 unsigned* __restrict__ cand) {
  __shared__ __align__(16) unsigned short Bl[2][32 * NK];  // 2 x 16KB dbuf
  __shared__ float ncsAll[1024];
  __shared__ float dpart[64];
  const int tid = threadIdx.x;
  const int w = tid >> 6, l = tid & 63, l15 = l & 15, l4 = l >> 4;
  const int rb = blockIdx.x >> 3, cs = blockIdx.x & 7;
  const int rowbase = rb * 64 + (w >> 1) * 32;
  const int wcol = (w & 1) * 16;          // 16-col half of the 32-col tile
  const int colslice = cs * 1024;

  if (tid < 64) dpart[tid] = 0.0f;
  #pragma unroll
  for (int j = 0; j < 4; ++j)
    ncsAll[tid + j * 256] = nrm[colslice + tid + j * 256];

  s8v A[2][8];  // 32 rows x K=256 in registers, reused across all 32 col-tiles
  #pragma unroll
  for (int rf = 0; rf < 2; ++rf) {
    const int rr = rowbase + rf * 16 + l15;
    #pragma unroll
    for (int kf = 0; kf < 8; ++kf) {
      const int g = ((kf << 2) | l4) ^ (rr & 7);
      A[rf][kf] = *reinterpret_cast<const s8v*>(xb + rr * NK + g * 8);
    }
  }
  float nr[2][4], dn[2][4];
  unsigned s0[2][4], s1[2][4];  // per-thread sorted top-2 keys per row
  #pragma unroll
  for (int rf = 0; rf < 2; ++rf)
    #pragma unroll
    for (int q = 0; q < 4; ++q) {
      nr[rf][q] = nrm[rowbase + rf * 16 + l4 * 4 + q];
      dn[rf][q] = 0.0f;
      s0[rf][q] = 0xFFFFFFFFu;
      s1[rf][q] = 0xFFFFFFFFu;
    }

  auto stage = [&](int buf, int t) {
    const unsigned short* src = xb + (colslice + t * 32) * NK;  // linear 16KB
    #pragma unroll
    for (int jj = 0; jj < 4; ++jj)
      gld16(src + (jj * 256 + tid) * 8, &Bl[buf][(jj * 256 + tid) * 8]);
  };

  const int dtb = rowbase - colslice;  // this wave's diag tile (32-col units)
  const int tdw = (dtb >= 0 && dtb < 1024) ? (dtb >> 5) : -1;
  // bounded 4-phase stagger, robust under chunked AND interleaved XCD maps
  const int t0 = (((rb >> 2) + (rb >> 5)) & 3) * 8;

  stage(0, t0);
  for (int i = 0; i < 32; ++i) {
    const int t = (t0 + i) & 31;
    const int cur = i & 1;
    __builtin_amdgcn_s_barrier();        // everyone done reading Bl[cur^1]
    __builtin_amdgcn_sched_barrier(0);
    if (i + 1 < 32) {
      stage(cur ^ 1, (t0 + i + 1) & 31); // prefetch next tile into other buf
      asm volatile("s_waitcnt vmcnt(4)" ::: "memory");  // Bl[cur] loads landed
    } else {
      asm volatile("s_waitcnt vmcnt(0)" ::: "memory");
    }
    __builtin_amdgcn_sched_barrier(0);
    const int cbase = colslice + t * 32;
    f32x4 acc[2];
    {
      f32x4 z = {0.f, 0.f, 0.f, 0.f};
      acc[0] = z; acc[1] = z;
    }
    #pragma unroll
    for (int kf = 0; kf < 8; ++kf) {
      const int gs = ((kf << 2) | l4) ^ (l15 & 7);
      const s8v b0 = *reinterpret_cast<const s8v*>(&Bl[cur][(wcol + l15) * NK + gs * 8]);
      acc[0] = __builtin_amdgcn_mfma_f32_16x16x32_bf16(A[0][kf], b0, acc[0], 0, 0, 0);
      acc[1] = __builtin_amdgcn_mfma_f32_16x16x32_bf16(A[1][kf], b0, acc[1], 0, 0, 0);
    }
    // branch-free epilogue: d, exp(-d) -> dn; top-2 key insert (3 min/max ops)
    const float nc0 = ncsAll[t * 32 + wcol + l15];
    const unsigned colg0 = (unsigned)(cbase + wcol + l15);
    auto epi = [&](auto dgc) {
      constexpr bool DG = decltype(dgc)::value;
      #pragma unroll
      for (int rf = 0; rf < 2; ++rf)
        #pragma unroll
        for (int q = 0; q < 4; ++q) {
          const unsigned rowg = (unsigned)(rowbase + rf * 16 + l4 * 4 + q);
          float sq0 = fmaf(acc[rf][q], -2.0f, nr[rf][q] + nc0);
          if (DG) sq0 = fmaxf(sq0, 0.0f);
          const float d0 = __builtin_amdgcn_sqrtf(sq0);
          float e0 = __expf(-d0);
          unsigned k0 = ((unsigned)__half_as_ushort(__float2half(d0)) << 16) | colg0;
          if (DG) {
            const bool nd0 = (rowg != colg0);
            e0 = nd0 ? e0 : 0.0f;
            k0 = nd0 ? k0 : 0xFFFFFFFFu;
          }
          dn[rf][q] += e0;
          const unsigned ev = umax32(s0[rf][q], k0);
          s0[rf][q] = umin32(s0[rf][q], k0);
          s1[rf][q] = umin32(s1[rf][q], ev);
        }
    };
    if (t == tdw) epi(BoolC<true>{});
    else          epi(BoolC<false>{});
  }
  // candidate writeback: cand[row][cs][whalf][l15][2] — NONTEMPORAL (don't
  // evict xb from L2; the stream is read exactly once, by k_fin)
  #pragma unroll
  for (int rf = 0; rf < 2; ++rf)
    #pragma unroll
    for (int q = 0; q < 4; ++q) {
      const int rowg = rowbase + rf * 16 + l4 * 4 + q;
      u32x2 pr; pr.x = s0[rf][q]; pr.y = s1[rf][q];
      __builtin_nontemporal_store(pr,
          reinterpret_cast<u32x2*>(&cand[rowg * 512 + cs * 64 + (w & 1) * 32 + l15 * 2]));
    }
  // per-row denom partial: shfl over the 16 lanes of a row, LDS-combine waves
  #pragma unroll
  for (int rf = 0; rf < 2; ++rf)
    #pragma unroll
    for (int q = 0; q < 4; ++q) {
      float vs = dn[rf][q];
      vs += __shfl_xor(vs, 1); vs += __shfl_xor(vs, 2);
      vs += __shfl_xor(vs, 4); vs += __shfl_xor(vs, 8);
      if (l15 == 0) atomicAdd(&dpart[(w >> 1) * 32 + rf * 16 + l4 * 4 + q], vs);
    }
  __syncthreads();
  if (tid < 64) dnp[(rb * 64 + tid) * 8 + cs] = dpart[tid];
}

// ----------------------------------------------------------------- k_fin ----
__global__ __launch_bounds__(256) void k_fin(const unsigned* __restrict__ cand,
                                             const float* __restrict__ dnp,
                                             const int* __restrict__ y,
                                             float* __restrict__ out) {
  const int w = threadIdx.x >> 6, l = threadIdx.x & 63;
  const int r = blockIdx.x * 4 + w;
  unsigned kk[8];
  const u32x4 pa = __builtin_nontemporal_load(
      reinterpret_cast<const u32x4*>(cand + r * 512 + l * 8));
  const u32x4 pb = __builtin_nontemporal_load(
      reinterpret_cast<const u32x4*>(cand + r * 512 + l * 8 + 4));
  kk[0] = pa.x; kk[1] = pa.y; kk[2] = pa.z; kk[3] = pa.w;
  kk[4] = pb.x; kk[5] = pb.y; kk[6] = pb.z; kk[7] = pb.w;
  unsigned myKey = 0xFFFFFFFFu;
  for (int pp = 0; pp < 16; ++pp) {
    unsigned lm = kk[0];
    #pragma unroll
    for (int j = 1; j < 8; ++j) lm = umin32(lm, kk[j]);
    unsigned m = lm;
    m = umin32(m, __shfl_xor(m, 1));  m = umin32(m, __shfl_xor(m, 2));
    m = umin32(m, __shfl_xor(m, 4));  m = umin32(m, __shfl_xor(m, 8));
    m = umin32(m, __shfl_xor(m, 16)); m = umin32(m, __shfl_xor(m, 32));
    const unsigned long long bal = __ballot(lm == m);
    const int owner = (int)__ffsll(bal) - 1;
    if (l == owner) {
      bool f = false;
      #pragma unroll
      for (int j = 0; j < 8; ++j)
        if (!f && kk[j] == m) { kk[j] = 0xFFFFFFFFu; f = true; }
    }
    if (l == pp) myKey = m;  // lanes 0..15 collect the 16 nearest keys
  }
  float den = 0.0f;
  #pragma unroll
  for (int cs = 0; cs < 8; ++cs) den += dnp[r * 8 + cs];
  const float logden = __logf(den);
  float contrib = 0.0f, cmf = 0.0f;
  if (l < 16 && myKey != 0xFFFFFFFFu) {
    const int col = (int)(myKey & 0x1FFFu);
    const float dd = __half2float(__ushort_as_half((unsigned short)(myKey >> 16)));
    if (y[col] == y[r]) { contrib = -dd - logden; cmf = 1.0f; }
  }
  contrib += __shfl_xor(contrib, 1);  contrib += __shfl_xor(contrib, 2);
  contrib += __shfl_xor(contrib, 4);  contrib += __shfl_xor(contrib, 8);
  contrib += __shfl_xor(contrib, 16); contrib += __shfl_xor(contrib, 32);
  cmf += __shfl_xor(cmf, 1);  cmf += __shfl_xor(cmf, 2);
  cmf += __shfl_xor(cmf, 4);  cmf += __shfl_xor(cmf, 8);
  cmf += __shfl_xor(cmf, 16); cmf += __shfl_xor(cmf, 32);
  if (l == 0 && cmf > 0.0f)
    atomicAdd(out, (contrib / cmf) * (-1.0f / 8192.0f));
}

// ---------------------------------------------------------------------------
extern "C" void kernel_launch(void* const* d_in, const int* in_sizes, int n_in,
                              void* d_out, int out_size, void* d_ws, size_t ws_size,
                              hipStream_t stream) {
  const float* x = (const float*)d_in[0];
  const int* y = (const int*)d_in[1];
  float* out = (float*)d_out;
  char* ws = (char*)d_ws;

  float*          dnp  = (float*)(ws + OFF_DNP);
  float*          nrm  = (float*)(ws + OFF_NRM);
  unsigned short* xb   = (unsigned short*)(ws + OFF_XB);
  unsigned*       cand = (unsigned*)(ws + OFF_CAND);

  k_prep<<<2048, 256, 0, stream>>>(x, xb, nrm, out);
  k_main<<<1024, 256, 0, stream>>>(xb, nrm, dnp, cand);
  k_fin <<<2048, 256, 0, stream>>>(cand, dnp, y, out);
}

// Round 13
// 110.696 us; speedup vs baseline: 1.2584x; 1.2584x over previous
//
#include <hip/hip_runtime.h>
#include <hip/hip_fp16.h>

// ---------------------------------------------------------------------------
// ClassificationKNNLoss on MI355X — R13 mega-kernel restructure.
//   k_prep : norms + bf16 convert with granule-XOR swizzle (+ zeroes d_out)
//   k_mega : ONE block per CU owns 32 rows x ALL 8192 cols. B-fragments read
//            DIRECT from global (L2-hot window; no write stream to evict it —
//            R6's failure driver). Zero barriers / zero LDS in the main loop.
//            Per-thread sorted top-2 keys + denom in regs; final top-16 +
//            label match + loss merged IN-BLOCK (k_fin, cand, dnp deleted).
// R10..R12 lessons: staged/barriered dataflow is a hard 80us local optimum;
// any tile-phase decorrelation thrashes the 4MiB/XCD L2; aux path cost 28us.
// ---------------------------------------------------------------------------

typedef __attribute__((ext_vector_type(8))) short s8v;       // 8 x bf16 (4 VGPR)
typedef __attribute__((ext_vector_type(4))) float f32x4;     // MFMA acc

#define NK 256

template <bool B> struct BoolC { static constexpr bool value = B; };

// ws byte offsets
#define OFF_NRM 0                // f32[8192]
#define OFF_XB  32768            // u16[8192*256] swizzled bf16 (4.19MB)

__device__ __forceinline__ unsigned short f2bf(float f) {
  unsigned u = __float_as_uint(f);
  return (unsigned short)((u + 0x7FFFu + ((u >> 16) & 1u)) >> 16);  // RNE
}

__device__ __forceinline__ unsigned umin32(unsigned a, unsigned b) { return a < b ? a : b; }
__device__ __forceinline__ unsigned umax32(unsigned a, unsigned b) { return a > b ? a : b; }

// ---------------------------------------------------------------- k_prep ----
// xb[(r,k)] stored at u16 index r*256 + ((k>>3) ^ (r&7))*8 + (k&7)
__global__ __launch_bounds__(256) void k_prep(const float* __restrict__ x,
                                              unsigned short* __restrict__ xb,
                                              float* __restrict__ nrm,
                                              float* __restrict__ out) {
  if (blockIdx.x == 0 && threadIdx.x == 0) out[0] = 0.0f;
  const int w = threadIdx.x >> 6, l = threadIdx.x & 63;
  const int r = blockIdx.x * 4 + w;
  const float4 xv = *reinterpret_cast<const float4*>(x + r * NK + l * 4);
  float ns = xv.x * xv.x + xv.y * xv.y + xv.z * xv.z + xv.w * xv.w;
  ns += __shfl_xor(ns, 1);  ns += __shfl_xor(ns, 2);  ns += __shfl_xor(ns, 4);
  ns += __shfl_xor(ns, 8);  ns += __shfl_xor(ns, 16); ns += __shfl_xor(ns, 32);
  if (l == 0) nrm[r] = ns;
  ushort4 bv;
  bv.x = f2bf(xv.x); bv.y = f2bf(xv.y); bv.z = f2bf(xv.z); bv.w = f2bf(xv.w);
  const int gs = (l >> 1) ^ (r & 7);
  *reinterpret_cast<ushort4*>(xb + r * NK + gs * 8 + (l & 1) * 4) = bv;
}

// ---------------------------------------------------------------- k_mega ----
// 256 blocks (1/CU) x 512 thr (8 waves). Block = rows [rb*32, rb*32+32).
// Wave w sweeps 64-col tiles t = w + 8i (i=0..15) -> tight global L2 window.
__global__ __launch_bounds__(512, 2) void k_mega(const unsigned short* __restrict__ xb,
                                                 const float* __restrict__ nrm,
                                                 const int* __restrict__ y,
                                                 float* __restrict__ out) {
  __shared__ float ncsAll[8192];      // all column norms (32KB)
  __shared__ float dpart[32];         // per-row denom
  __shared__ unsigned cl[32][256];    // per-row candidate lists (32KB)
  const int tid = threadIdx.x;
  const int w = tid >> 6, l = tid & 63, l15 = l & 15, l4 = l >> 4;
  const int rb = blockIdx.x;
  const int rowbase = rb * 32;

  #pragma unroll
  for (int j = 0; j < 16; ++j) ncsAll[tid + j * 512] = nrm[tid + j * 512];
  if (tid < 32) dpart[tid] = 0.0f;

  s8v A[2][8];  // this wave's 32 rows x K=256, register-resident
  #pragma unroll
  for (int rf = 0; rf < 2; ++rf) {
    const int rr = rowbase + rf * 16 + l15;
    #pragma unroll
    for (int kf = 0; kf < 8; ++kf) {
      const int g = ((kf << 2) | l4) ^ (rr & 7);
      A[rf][kf] = *reinterpret_cast<const s8v*>(xb + rr * NK + g * 8);
    }
  }
  float nr[2][4], dn[2][4];
  unsigned s0[2][4], s1[2][4];  // per-thread sorted top-2 keys per row
  #pragma unroll
  for (int rf = 0; rf < 2; ++rf)
    #pragma unroll
    for (int q = 0; q < 4; ++q) {
      nr[rf][q] = nrm[rowbase + rf * 16 + l4 * 4 + q];
      dn[rf][q] = 0.0f;
      s0[rf][q] = 0xFFFFFFFFu;
      s1[rf][q] = 0xFFFFFFFFu;
    }

  int koff[8];  // per-lane granule byte offset within a column's 512B row
  #pragma unroll
  for (int kf = 0; kf < 8; ++kf)
    koff[kf] = ((((kf << 2) | l4) ^ (l15 & 7)) << 4);
  const char* xbc = (const char*)xb;
  const int tdg = rb >> 1;            // tile containing this block's diagonal

  __syncthreads();                    // ncsAll/dpart published

  for (int i = 0; i < 16; ++i) {
    const int t = w + i * 8;
    const int cbase = t * 64;
    const char* bp = xbc + (size_t)(cbase + l15) * 512;
    f32x4 acc[2][4];
    #pragma unroll
    for (int cf = 0; cf < 4; ++cf) {
      f32x4 z = {0.f, 0.f, 0.f, 0.f};
      acc[0][cf] = z; acc[1][cf] = z;
    }
    #pragma unroll
    for (int kf = 0; kf < 8; ++kf) {
      const s8v b0 = *reinterpret_cast<const s8v*>(bp + koff[kf]);
      const s8v b1 = *reinterpret_cast<const s8v*>(bp + 8192 + koff[kf]);
      const s8v b2 = *reinterpret_cast<const s8v*>(bp + 16384 + koff[kf]);
      const s8v b3 = *reinterpret_cast<const s8v*>(bp + 24576 + koff[kf]);
      acc[0][0] = __builtin_amdgcn_mfma_f32_16x16x32_bf16(A[0][kf], b0, acc[0][0], 0, 0, 0);
      acc[1][0] = __builtin_amdgcn_mfma_f32_16x16x32_bf16(A[1][kf], b0, acc[1][0], 0, 0, 0);
      acc[0][1] = __builtin_amdgcn_mfma_f32_16x16x32_bf16(A[0][kf], b1, acc[0][1], 0, 0, 0);
      acc[1][1] = __builtin_amdgcn_mfma_f32_16x16x32_bf16(A[1][kf], b1, acc[1][1], 0, 0, 0);
      acc[0][2] = __builtin_amdgcn_mfma_f32_16x16x32_bf16(A[0][kf], b2, acc[0][2], 0, 0, 0);
      acc[1][2] = __builtin_amdgcn_mfma_f32_16x16x32_bf16(A[1][kf], b2, acc[1][2], 0, 0, 0);
      acc[0][3] = __builtin_amdgcn_mfma_f32_16x16x32_bf16(A[0][kf], b3, acc[0][3], 0, 0, 0);
      acc[1][3] = __builtin_amdgcn_mfma_f32_16x16x32_bf16(A[1][kf], b3, acc[1][3], 0, 0, 0);
    }
    float nc[4];
    #pragma unroll
    for (int cf = 0; cf < 4; ++cf) nc[cf] = ncsAll[cbase + cf * 16 + l15];
    auto epi = [&](auto dgc) {
      constexpr bool DG = decltype(dgc)::value;
      #pragma unroll
      for (int rf = 0; rf < 2; ++rf)
        #pragma unroll
        for (int cf = 0; cf < 4; ++cf) {
          const unsigned colg = (unsigned)(cbase + cf * 16 + l15);
          #pragma unroll
          for (int q = 0; q < 4; ++q) {
            const unsigned rowg = (unsigned)(rowbase + rf * 16 + l4 * 4 + q);
            float sq = fmaf(acc[rf][cf][q], -2.0f, nr[rf][q] + nc[cf]);
            if (DG) sq = fmaxf(sq, 0.0f);
            const float d = __builtin_amdgcn_sqrtf(sq);
            float e = __expf(-d);
            unsigned k = ((unsigned)__half_as_ushort(__float2half(d)) << 16) | colg;
            if (DG) {
              const bool nd = (rowg != colg);
              e = nd ? e : 0.0f;
              k = nd ? k : 0xFFFFFFFFu;
            }
            dn[rf][q] += e;
            const unsigned ev = umax32(s0[rf][q], k);
            s0[rf][q] = umin32(s0[rf][q], k);
            s1[rf][q] = umin32(s1[rf][q], ev);
          }
        }
    };
    if (t == tdg) epi(BoolC<true>{});
    else          epi(BoolC<false>{});
  }

  // ---- in-block merge (replaces k_fin) ----
  #pragma unroll
  for (int rf = 0; rf < 2; ++rf)
    #pragma unroll
    for (int q = 0; q < 4; ++q) {
      float vs = dn[rf][q];
      vs += __shfl_xor(vs, 1); vs += __shfl_xor(vs, 2);
      vs += __shfl_xor(vs, 4); vs += __shfl_xor(vs, 8);
      const int row32 = rf * 16 + l4 * 4 + q;
      if (l15 == 0) atomicAdd(&dpart[row32], vs);
      cl[row32][w * 32 + l15 * 2]     = s0[rf][q];
      cl[row32][w * 32 + l15 * 2 + 1] = s1[rf][q];
    }
  __syncthreads();

  float wsum = 0.0f;
  for (int rr = 0; rr < 4; ++rr) {   // wave w finalizes rows 4w..4w+3
    const int row = w * 4 + rr;
    unsigned kk[4];
    #pragma unroll
    for (int j = 0; j < 4; ++j) kk[j] = cl[row][l * 4 + j];
    unsigned myKey = 0xFFFFFFFFu;
    for (int pp = 0; pp < 16; ++pp) {
      const unsigned lm = umin32(umin32(kk[0], kk[1]), umin32(kk[2], kk[3]));
      unsigned m = lm;
      m = umin32(m, __shfl_xor(m, 1));  m = umin32(m, __shfl_xor(m, 2));
      m = umin32(m, __shfl_xor(m, 4));  m = umin32(m, __shfl_xor(m, 8));
      m = umin32(m, __shfl_xor(m, 16)); m = umin32(m, __shfl_xor(m, 32));
      const unsigned long long bal = __ballot(lm == m);
      const int owner = (int)__ffsll(bal) - 1;
      if (l == owner) {
        bool f = false;
        #pragma unroll
        for (int j = 0; j < 4; ++j)
          if (!f && kk[j] == m) { kk[j] = 0xFFFFFFFFu; f = true; }
      }
      if (l == pp) myKey = m;
    }
    const float logden = __logf(dpart[row]);
    float contrib = 0.0f, cmf = 0.0f;
    if (l < 16 && myKey != 0xFFFFFFFFu) {
      const int col = (int)(myKey & 0x1FFFu);
      const float dd = __half2float(__ushort_as_half((unsigned short)(myKey >> 16)));
      if (y[col] == y[rowbase + row]) { contrib = -dd - logden; cmf = 1.0f; }
    }
    contrib += __shfl_xor(contrib, 1);  contrib += __shfl_xor(contrib, 2);
    contrib += __shfl_xor(contrib, 4);  contrib += __shfl_xor(contrib, 8);
    contrib += __shfl_xor(contrib, 16); contrib += __shfl_xor(contrib, 32);
    cmf += __shfl_xor(cmf, 1);  cmf += __shfl_xor(cmf, 2);
    cmf += __shfl_xor(cmf, 4);  cmf += __shfl_xor(cmf, 8);
    cmf += __shfl_xor(cmf, 16); cmf += __shfl_xor(cmf, 32);
    if (cmf > 0.0f) wsum += contrib / cmf;
  }
  if (l == 0) atomicAdd(out, wsum * (-1.0f / 8192.0f));
}

// ---------------------------------------------------------------------------
extern "C" void kernel_launch(void* const* d_in, const int* in_sizes, int n_in,
                              void* d_out, int out_size, void* d_ws, size_t ws_size,
                              hipStream_t stream) {
  const float* x = (const float*)d_in[0];
  const int* y = (const int*)d_in[1];
  float* out = (float*)d_out;
  char* ws = (char*)d_ws;

  float*          nrm = (float*)(ws + OFF_NRM);
  unsigned short* xb  = (unsigned short*)(ws + OFF_XB);

  k_prep<<<2048, 256, 0, stream>>>(x, xb, nrm, out);
  k_mega<<<256,  512, 0, stream>>>(xb, nrm, y, out);
}